// Round 17
// baseline (177.410 us; speedup 1.0000x reference)
//
#include <hip/hip_runtime.h>

typedef unsigned short u16;
typedef unsigned int u32;
typedef short bf16x8 __attribute__((ext_vector_type(8)));
typedef float f32x4 __attribute__((ext_vector_type(4)));

#define HH 128

__device__ __forceinline__ u16 f2bf(float f) {
  u32 u = __float_as_uint(f);
  u += 0x7fffu + ((u >> 16) & 1u);  // round-to-nearest-even
  return (u16)(u >> 16);
}
__device__ __forceinline__ u32 pack2(float a, float b) {
  return (u32)f2bf(a) | ((u32)f2bf(b) << 16);
}
__device__ __forceinline__ float bf2f(u16 h) {
  return __uint_as_float(((u32)h) << 16);
}
__device__ __forceinline__ u32 cvtpk(float lo, float hi) {
  u32 r;
  asm("v_cvt_pk_bf16_f32 %0, %1, %2" : "=v"(r) : "v"(lo), "v"(hi));
  return r;
}

// ---------------------------------------------------------------------------
// Pre-pass: fused W_comb (bf16), chunk-transposed + bank-swizzled, into d_ws.
// Chunk index (((q*16+kc)*512+n)*4+p) holds W[k = kc*32 + lq*8 + j][col n],
// lq = p ^ (n&3) ^ ((n>>2)&3).
// Fused: k<384 -> W_cat[k][q*512+n]; k>=384 -> (n<128 ? 0 : W_exp[k-384][q*384+n-128])
// ---------------------------------------------------------------------------
__global__ __launch_bounds__(256) void prep_w(const float* __restrict__ Wcat,
                                              const float* __restrict__ Wexp,
                                              u16* __restrict__ Wc) {
  const int bx = blockIdx.x;      // 512 blocks: ((q*16+kc)*8 + nt)
  const int nt = bx & 7;
  const int kc = (bx >> 3) & 15;
  const int q = bx >> 7;
  __shared__ u16 T[32 * 72];      // [k-in-chunk][64 cols], stride 72 (pad)

  const int tid = threadIdx.x;
  const int r = tid >> 3;
  const int c8 = (tid & 7) * 8;
  float v[8];
  if (kc < 12) {
    const float* src =
        Wcat + (size_t)(kc * 32 + r) * 2048 + q * 512 + nt * 64 + c8;
    float4 a = *(const float4*)src;
    float4 b = *(const float4*)(src + 4);
    v[0] = a.x; v[1] = a.y; v[2] = a.z; v[3] = a.w;
    v[4] = b.x; v[5] = b.y; v[6] = b.z; v[7] = b.w;
  } else if (nt >= 2) {
    const float* src = Wexp + (size_t)((kc - 12) * 32 + r) * 1536 + q * 384 +
                       nt * 64 + c8 - 128;
    float4 a = *(const float4*)src;
    float4 b = *(const float4*)(src + 4);
    v[0] = a.x; v[1] = a.y; v[2] = a.z; v[3] = a.w;
    v[4] = b.x; v[5] = b.y; v[6] = b.z; v[7] = b.w;
  } else {
#pragma unroll
    for (int j = 0; j < 8; ++j) v[j] = 0.f;
  }
  uint4 pk;
  pk.x = pack2(v[0], v[1]);
  pk.y = pack2(v[2], v[3]);
  pk.z = pack2(v[4], v[5]);
  pk.w = pack2(v[6], v[7]);
  *(uint4*)&T[r * 72 + c8] = pk;
  __syncthreads();

  const int p = tid & 3;
  const int nl = tid >> 2;  // 0..63 local col
  const int lq = p ^ (nl & 3) ^ ((nl >> 2) & 3);
  u16 w[8];
#pragma unroll
  for (int j = 0; j < 8; ++j) w[j] = T[(lq * 8 + j) * 72 + nl];
  uint4 o;
  o.x = (u32)w[0] | ((u32)w[1] << 16);
  o.y = (u32)w[2] | ((u32)w[3] << 16);
  o.z = (u32)w[4] | ((u32)w[5] << 16);
  o.w = (u32)w[6] | ((u32)w[7] << 16);
  const size_t idx = ((size_t)((q * 16 + kc) * 512) + nt * 64 + nl) * 4 + p;
  ((uint4*)Wc)[idx] = o;
}

// ---------------------------------------------------------------------------
// R3: R1 geometry (64-row tile, 1024 blocks, 8 waves) + B via global_load_lds
// into a 2x32KB LDS double-buffer, counted vmcnt(4) (never drained in-loop),
// raw s_barrier x2 per kc phase (T3+T4 recipe). A staged once in LDS (R1
// layout verbatim); epilogue verbatim R1. LDS 128KB -> 1 block/CU; m201
// precedent: counted-vmcnt pipeline at 2 waves/SIMD beats uncounted at 4.
// Sync audit (r16): per-wave vmcnt(4) before BAR_A => all waves' chunk-kc
// loads in LDS after BAR_A; WAR safe (issue after BAR_B of same parity).
// ---------------------------------------------------------------------------
__global__ __launch_bounds__(512, 2) void fused_gate(
    const float* __restrict__ CNN, const float* __restrict__ gaz,
    const float* __restrict__ gazb, const float* __restrict__ gm,
    const float* __restrict__ exper, const u16* __restrict__ Wc,
    const float* __restrict__ bcat, const float* __restrict__ bexp,
    float* __restrict__ out) {
  __shared__ u16 Abuf[16 * 64 * 32];  // 64 KB
  __shared__ u16 Bbuf[2 * 16384];     // 2 x 32 KB kc-chunks

  const int tid = threadIdx.x;
  const int lane = tid & 63;
  const int wave = tid >> 6;  // 0..7
  const int bx = blockIdx.x;  // 1024: grp*8 + tile
  const int tile = bx & 7;
  const int grp = bx >> 3;
  const int b = grp >> 2;
  const int q = grp & 3;
  const int s_base = tile * 64;

  // ---- stage A (R1 verbatim, cvtpk for pack): wave pair sel loads source;
  //      wave&1 picks the 32-row half ----
  const int sel = wave >> 1;
  const float* src_w =
      (sel == 0) ? CNN + (size_t)(b * 2048 + q * 512 + s_base) * HH
      : (sel == 1) ? (((q & 1) ? gazb : gaz) + (size_t)(b * 512 + s_base) * HH)
      : (sel == 2) ? gm + (size_t)(b * 512 + s_base) * HH
                   : exper + (size_t)(b * 512 + s_base) * HH;
#pragma unroll
  for (int t = 0; t < 8; ++t) {
    const int s = t * 64 + lane;            // 0..511
    const int row = (wave & 1) * 32 + (s >> 4);
    const int oct = s & 15;                 // 16B-octet within 128-feat row
    const float* sp = src_w + (size_t)row * HH + oct * 8;
    float4 f0 = *(const float4*)sp;
    float4 f1 = *(const float4*)(sp + 4);
    uint4 pk;
    pk.x = cvtpk(f0.x, f0.y);
    pk.y = cvtpk(f0.z, f0.w);
    pk.z = cvtpk(f1.x, f1.y);
    pk.w = cvtpk(f1.z, f1.w);
    const int kc = sel * 4 + (oct >> 2);
    const int o = oct & 3;
    const int ph = o ^ ((row & 3) ^ ((row >> 2) & 3)) ^ sel;  // kc>>2 == sel
    *(uint4*)&Abuf[(kc * 64 + row) * 32 + ph * 8] = pk;
  }

  // ---- K-loop setup ----
  const int l15 = lane & 15;
  const int quad = lane >> 4;
  const int sl = (l15 & 3) ^ ((l15 >> 2) & 3);
  const int physB = quad ^ sl;
  const char* __restrict__ Wq = (const char*)(Wc + (size_t)q * 262144);
  u32 offb[4];
#pragma unroll
  for (int gg = 0; gg < 4; ++gg) {
    const int n = gg * 128 + wave * 16 + l15;
    offb[gg] = (u32)((n * 4 + physB) * 16);
  }

  // B gload bases: block-wide linear copy of each 32KB kc-chunk.
  // thread t covers bytes t*16 + i*8192 (wave-uniform LDS dest + lane*16).
  const char* gB = Wq + (size_t)(wave * 1024 + lane * 16);
  u16* bw0 = &Bbuf[wave * 512];            // u16 idx = bytes/2
  u16* bw1 = &Bbuf[16384 + wave * 512];

  f32x4 acc[4][4];
#pragma unroll
  for (int rt = 0; rt < 4; ++rt)
#pragma unroll
    for (int gg = 0; gg < 4; ++gg) acc[rt][gg] = (f32x4)0.f;

  // prologue: issue kc=0 chunk into buf0 (before the stage barrier; the
  // __syncthreads below also covers A-stage visibility)
#pragma unroll
  for (int i = 0; i < 4; ++i)
    __builtin_amdgcn_global_load_lds((const u32*)(gB + i * 8192),
                                     (u32*)(bw0 + i * 4096), 16, 0, 0);
  __syncthreads();  // A staged + (drains vmcnt once — prologue only)

  // re-issue kc=0? No: __syncthreads drained vmcnt(0) -> buf0 already valid.
#pragma unroll
  for (int kc = 0; kc < 16; ++kc) {
    // (1) issue gloads for kc+1 into the other buffer
    if (kc < 15) {
      const char* g = gB + (size_t)(kc + 1) * 32768;
      u16* d = ((kc + 1) & 1) ? bw1 : bw0;
#pragma unroll
      for (int i = 0; i < 4; ++i)
        __builtin_amdgcn_global_load_lds((const u32*)(g + i * 8192),
                                         (u32*)(d + i * 4096), 16, 0, 0);
    }
    // (2) counted wait: kc's chunk landed, kc+1's 4 loads stay in flight
    if (kc < 15)
      asm volatile("s_waitcnt vmcnt(4)" ::: "memory");
    else
      asm volatile("s_waitcnt vmcnt(0)" ::: "memory");
    __builtin_amdgcn_sched_barrier(0);
    __builtin_amdgcn_s_barrier();  // BAR_A: buf[kc&1] valid block-wide
    __builtin_amdgcn_sched_barrier(0);

    // (3) fragments + MFMA
    const u16* bb = &Bbuf[(kc & 1) * 16384];
    bf16x8 bf0 = *(const bf16x8*)((const char*)bb + offb[0]);
    bf16x8 bf1 = *(const bf16x8*)((const char*)bb + offb[1]);
    bf16x8 bf2 = *(const bf16x8*)((const char*)bb + offb[2]);
    bf16x8 bf3 = *(const bf16x8*)((const char*)bb + offb[3]);
    const int pa = (quad ^ sl ^ (kc >> 2)) * 8;
    const u16* ab = &Abuf[(kc * 64 + l15) * 32 + pa];
    bf16x8 af0 = *(const bf16x8*)(ab);
    bf16x8 af1 = *(const bf16x8*)(ab + 16 * 32);
    __builtin_amdgcn_s_setprio(1);
    acc[0][0] = __builtin_amdgcn_mfma_f32_16x16x32_bf16(af0, bf0, acc[0][0], 0, 0, 0);
    acc[0][1] = __builtin_amdgcn_mfma_f32_16x16x32_bf16(af0, bf1, acc[0][1], 0, 0, 0);
    acc[0][2] = __builtin_amdgcn_mfma_f32_16x16x32_bf16(af0, bf2, acc[0][2], 0, 0, 0);
    acc[0][3] = __builtin_amdgcn_mfma_f32_16x16x32_bf16(af0, bf3, acc[0][3], 0, 0, 0);
    acc[1][0] = __builtin_amdgcn_mfma_f32_16x16x32_bf16(af1, bf0, acc[1][0], 0, 0, 0);
    acc[1][1] = __builtin_amdgcn_mfma_f32_16x16x32_bf16(af1, bf1, acc[1][1], 0, 0, 0);
    acc[1][2] = __builtin_amdgcn_mfma_f32_16x16x32_bf16(af1, bf2, acc[1][2], 0, 0, 0);
    acc[1][3] = __builtin_amdgcn_mfma_f32_16x16x32_bf16(af1, bf3, acc[1][3], 0, 0, 0);
    __builtin_amdgcn_s_setprio(0);
    bf16x8 af2 = *(const bf16x8*)(ab + 32 * 32);
    bf16x8 af3 = *(const bf16x8*)(ab + 48 * 32);
    __builtin_amdgcn_s_setprio(1);
    acc[2][0] = __builtin_amdgcn_mfma_f32_16x16x32_bf16(af2, bf0, acc[2][0], 0, 0, 0);
    acc[2][1] = __builtin_amdgcn_mfma_f32_16x16x32_bf16(af2, bf1, acc[2][1], 0, 0, 0);
    acc[2][2] = __builtin_amdgcn_mfma_f32_16x16x32_bf16(af2, bf2, acc[2][2], 0, 0, 0);
    acc[2][3] = __builtin_amdgcn_mfma_f32_16x16x32_bf16(af2, bf3, acc[2][3], 0, 0, 0);
    acc[3][0] = __builtin_amdgcn_mfma_f32_16x16x32_bf16(af3, bf0, acc[3][0], 0, 0, 0);
    acc[3][1] = __builtin_amdgcn_mfma_f32_16x16x32_bf16(af3, bf1, acc[3][1], 0, 0, 0);
    acc[3][2] = __builtin_amdgcn_mfma_f32_16x16x32_bf16(af3, bf2, acc[3][2], 0, 0, 0);
    acc[3][3] = __builtin_amdgcn_mfma_f32_16x16x32_bf16(af3, bf3, acc[3][3], 0, 0, 0);
    __builtin_amdgcn_s_setprio(0);
    __builtin_amdgcn_sched_barrier(0);
    __builtin_amdgcn_s_barrier();  // BAR_B: all reads of buf[kc&1] done
    __builtin_amdgcn_sched_barrier(0);
  }

  // ---- epilogue (R1 verbatim): tanh / sigmoid / softmax-of-3 / sum ----
  const float* bcq = bcat + q * 512;
  const float* beq = bexp + q * 384;
  const size_t outbase = (size_t)((q * 32 + b) * 512 + s_base) * HH;
  const int h = wave * 16 + l15;  // 0..127
  const float bc0 = bcq[h];
  const float bc1 = bcq[128 + h];
  const float bc2 = bcq[256 + h];
  const float bc3 = bcq[384 + h];
  const float be1 = beq[h];
  const float be2 = beq[128 + h];
  const float be3 = beq[256 + h];
  const int kcc = h >> 5;         // CNN chunk (0..3)
  const int kce = 12 + (h >> 5);  // exper chunk (12..15)
  const int oh = (h >> 3) & 3;
  const int he = h & 7;
#pragma unroll
  for (int rt = 0; rt < 4; ++rt) {
#pragma unroll
    for (int r = 0; r < 4; ++r) {
      const int row = rt * 16 + quad * 4 + r;
      const int srw = (row & 3) ^ ((row >> 2) & 3);
      const float cnn = bf2f(Abuf[(kcc * 64 + row) * 32 + (oh ^ srw) * 8 + he]);
      const float ex =
          bf2f(Abuf[(kce * 64 + row) * 32 + (oh ^ srw ^ 3) * 8 + he]);
      const float c0 = acc[rt][0][r] + bc0;
      const float p1 = acc[rt][1][r] + bc1 + be1;
      const float p2 = acc[rt][2][r] + bc2 + be2;
      const float p3 = acc[rt][3][r] + bc3 + be3;
      const float e2c = __expf(2.f * c0);
      const float ns = 1.f - 2.f * __builtin_amdgcn_rcpf(e2c + 1.f);  // tanh
      const float g1 = __builtin_amdgcn_rcpf(1.f + __expf(-p1));
      const float g2 = __builtin_amdgcn_rcpf(1.f + __expf(-p2));
      const float g3 = __builtin_amdgcn_rcpf(1.f + __expf(-p3));
      const float e1 = __expf(g1);
      const float e2 = __expf(g2);
      const float e3 = __expf(g3);
      const float inv = __builtin_amdgcn_rcpf(e1 + e2 + e3);
      out[outbase + (size_t)row * HH + h] = (e1 * ns + e2 * cnn + e3 * ex) * inv;
    }
  }
}

extern "C" void kernel_launch(void* const* d_in, const int* in_sizes, int n_in,
                              void* d_out, int out_size, void* d_ws, size_t ws_size,
                              hipStream_t stream) {
  const float* CNN = (const float*)d_in[0];
  const float* gaz = (const float*)d_in[1];
  const float* gazb = (const float*)d_in[2];
  const float* gm = (const float*)d_in[3];
  const float* exper = (const float*)d_in[4];
  const float* Wcat = (const float*)d_in[5];
  const float* bcat = (const float*)d_in[6];
  const float* Wexp = (const float*)d_in[7];
  const float* bexp = (const float*)d_in[8];
  u16* Wc = (u16*)d_ws;  // 2 MB fused bf16 weights

  prep_w<<<512, 256, 0, stream>>>(Wcat, Wexp, Wc);
  fused_gate<<<1024, 512, 0, stream>>>(CNN, gaz, gazb, gm, exper, Wc, bcat,
                                       bexp, (float*)d_out);
}

// Round 21
// 152.569 us; speedup vs baseline: 1.1628x; 1.1628x over previous
//
#include <hip/hip_runtime.h>

typedef unsigned short u16;
typedef unsigned int u32;
typedef short bf16x8 __attribute__((ext_vector_type(8)));
typedef float f32x4 __attribute__((ext_vector_type(4)));

#define HH 128

__device__ __forceinline__ u16 f2bf(float f) {
  u32 u = __float_as_uint(f);
  u += 0x7fffu + ((u >> 16) & 1u);  // round-to-nearest-even
  return (u16)(u >> 16);
}
__device__ __forceinline__ u32 pack2(float a, float b) {
  return (u32)f2bf(a) | ((u32)f2bf(b) << 16);
}
__device__ __forceinline__ float bf2f(u16 h) {
  return __uint_as_float(((u32)h) << 16);
}

// ---------------------------------------------------------------------------
// Pre-pass: fused W_comb (bf16), chunk-transposed + bank-swizzled, into d_ws.
// Chunk index (((q*16+kc)*512+n)*4+p) holds W[k = kc*32 + lq*8 + j][col n],
// lq = p ^ (n&3) ^ ((n>>2)&3).
// Fused: k<384 -> W_cat[k][q*512+n]; k>=384 -> (n<128 ? 0 : W_exp[k-384][q*384+n-128])
// ---------------------------------------------------------------------------
__global__ __launch_bounds__(256) void prep_w(const float* __restrict__ Wcat,
                                              const float* __restrict__ Wexp,
                                              u16* __restrict__ Wc) {
  const int bx = blockIdx.x;      // 512 blocks: ((q*16+kc)*8 + nt)
  const int nt = bx & 7;
  const int kc = (bx >> 3) & 15;
  const int q = bx >> 7;
  __shared__ u16 T[32 * 72];      // [k-in-chunk][64 cols], stride 72 (pad)

  const int tid = threadIdx.x;
  const int r = tid >> 3;
  const int c8 = (tid & 7) * 8;
  float v[8];
  if (kc < 12) {
    const float* src =
        Wcat + (size_t)(kc * 32 + r) * 2048 + q * 512 + nt * 64 + c8;
    float4 a = *(const float4*)src;
    float4 b = *(const float4*)(src + 4);
    v[0] = a.x; v[1] = a.y; v[2] = a.z; v[3] = a.w;
    v[4] = b.x; v[5] = b.y; v[6] = b.z; v[7] = b.w;
  } else if (nt >= 2) {
    const float* src = Wexp + (size_t)((kc - 12) * 32 + r) * 1536 + q * 384 +
                       nt * 64 + c8 - 128;
    float4 a = *(const float4*)src;
    float4 b = *(const float4*)(src + 4);
    v[0] = a.x; v[1] = a.y; v[2] = a.z; v[3] = a.w;
    v[4] = b.x; v[5] = b.y; v[6] = b.z; v[7] = b.w;
  } else {
#pragma unroll
    for (int j = 0; j < 8; ++j) v[j] = 0.f;
  }
  uint4 pk;
  pk.x = pack2(v[0], v[1]);
  pk.y = pack2(v[2], v[3]);
  pk.z = pack2(v[4], v[5]);
  pk.w = pack2(v[6], v[7]);
  *(uint4*)&T[r * 72 + c8] = pk;
  __syncthreads();

  const int p = tid & 3;
  const int nl = tid >> 2;  // 0..63 local col
  const int lq = p ^ (nl & 3) ^ ((nl >> 2) & 3);
  u16 w[8];
#pragma unroll
  for (int j = 0; j < 8; ++j) w[j] = T[(lq * 8 + j) * 72 + nl];
  uint4 o;
  o.x = (u32)w[0] | ((u32)w[1] << 16);
  o.y = (u32)w[2] | ((u32)w[3] << 16);
  o.z = (u32)w[4] | ((u32)w[5] << 16);
  o.w = (u32)w[6] | ((u32)w[7] << 16);
  const size_t idx = ((size_t)((q * 16 + kc) * 512) + nt * 64 + nl) * 4 + p;
  ((uint4*)Wc)[idx] = o;
}

// ---------------------------------------------------------------------------
// R4 = measured-best R1 + even/odd B register double-buffer (kills the 16
// v_mov bnxt->bcur copies per kc; identical memory sequence & math).
// Fused GEMM + gate epilogue — barrier-free K-loop, 8-wave blocks.
// Block: (b,q) x 64-row tile x FULL 128-h slab; wave w owns cols
// {gg*128 + w*16 + c}. A staged once in LDS (one barrier); B streamed
// global->VGPR (L2-resident), 1-deep prefetch, alternating bA/bB sets.
// 2 blocks/CU (128 KB LDS) = 4 waves/SIMD. 64 VGPR + 64 AGPR = 128 (no spill).
// A LDS layout: [kc][row][32k], phys octet p = o ^ s(row) ^ (kc>>2),
// s(row) = (row&3)^((row>>2)&3).
// ---------------------------------------------------------------------------
#define MFMA_BODY(KC, BREG)                                                    \
  {                                                                            \
    const int pa = (quad ^ sl ^ ((KC) >> 2)) * 8;                              \
    const u16* ab = &Abuf[((KC)*64 + l15) * 32 + pa];                          \
    bf16x8 af0 = *(const bf16x8*)(ab);                                         \
    bf16x8 af1 = *(const bf16x8*)(ab + 16 * 32);                               \
    __builtin_amdgcn_s_setprio(1);                                             \
    acc[0][0] = __builtin_amdgcn_mfma_f32_16x16x32_bf16(af0, BREG[0], acc[0][0], 0, 0, 0); \
    acc[0][1] = __builtin_amdgcn_mfma_f32_16x16x32_bf16(af0, BREG[1], acc[0][1], 0, 0, 0); \
    acc[0][2] = __builtin_amdgcn_mfma_f32_16x16x32_bf16(af0, BREG[2], acc[0][2], 0, 0, 0); \
    acc[0][3] = __builtin_amdgcn_mfma_f32_16x16x32_bf16(af0, BREG[3], acc[0][3], 0, 0, 0); \
    acc[1][0] = __builtin_amdgcn_mfma_f32_16x16x32_bf16(af1, BREG[0], acc[1][0], 0, 0, 0); \
    acc[1][1] = __builtin_amdgcn_mfma_f32_16x16x32_bf16(af1, BREG[1], acc[1][1], 0, 0, 0); \
    acc[1][2] = __builtin_amdgcn_mfma_f32_16x16x32_bf16(af1, BREG[2], acc[1][2], 0, 0, 0); \
    acc[1][3] = __builtin_amdgcn_mfma_f32_16x16x32_bf16(af1, BREG[3], acc[1][3], 0, 0, 0); \
    __builtin_amdgcn_s_setprio(0);                                             \
    bf16x8 af2 = *(const bf16x8*)(ab + 32 * 32);                               \
    bf16x8 af3 = *(const bf16x8*)(ab + 48 * 32);                               \
    __builtin_amdgcn_s_setprio(1);                                             \
    acc[2][0] = __builtin_amdgcn_mfma_f32_16x16x32_bf16(af2, BREG[0], acc[2][0], 0, 0, 0); \
    acc[2][1] = __builtin_amdgcn_mfma_f32_16x16x32_bf16(af2, BREG[1], acc[2][1], 0, 0, 0); \
    acc[2][2] = __builtin_amdgcn_mfma_f32_16x16x32_bf16(af2, BREG[2], acc[2][2], 0, 0, 0); \
    acc[2][3] = __builtin_amdgcn_mfma_f32_16x16x32_bf16(af2, BREG[3], acc[2][3], 0, 0, 0); \
    acc[3][0] = __builtin_amdgcn_mfma_f32_16x16x32_bf16(af3, BREG[0], acc[3][0], 0, 0, 0); \
    acc[3][1] = __builtin_amdgcn_mfma_f32_16x16x32_bf16(af3, BREG[1], acc[3][1], 0, 0, 0); \
    acc[3][2] = __builtin_amdgcn_mfma_f32_16x16x32_bf16(af3, BREG[2], acc[3][2], 0, 0, 0); \
    acc[3][3] = __builtin_amdgcn_mfma_f32_16x16x32_bf16(af3, BREG[3], acc[3][3], 0, 0, 0); \
    __builtin_amdgcn_s_setprio(0);                                             \
  }

__global__ __launch_bounds__(512, 4) void fused_gate(
    const float* __restrict__ CNN, const float* __restrict__ gaz,
    const float* __restrict__ gazb, const float* __restrict__ gm,
    const float* __restrict__ exper, const u16* __restrict__ Wc,
    const float* __restrict__ bcat, const float* __restrict__ bexp,
    float* __restrict__ out) {
  __shared__ u16 Abuf[16 * 64 * 32];  // 64 KB

  const int tid = threadIdx.x;
  const int lane = tid & 63;
  const int wave = tid >> 6;  // 0..7
  const int bx = blockIdx.x;  // 1024: grp*8 + tile
  const int tile = bx & 7;
  const int grp = bx >> 3;
  const int b = grp >> 2;
  const int q = grp & 3;
  const int s_base = tile * 64;

  // ---- stage A: wave pair (sel = wave>>1) loads source sel; wave&1 picks
  //      the 32-row half. Each wave: 32 rows x 128 feats (16 KB fp32).
  const int sel = wave >> 1;
  const float* src_w =
      (sel == 0) ? CNN + (size_t)(b * 2048 + q * 512 + s_base) * HH
      : (sel == 1) ? (((q & 1) ? gazb : gaz) + (size_t)(b * 512 + s_base) * HH)
      : (sel == 2) ? gm + (size_t)(b * 512 + s_base) * HH
                   : exper + (size_t)(b * 512 + s_base) * HH;
#pragma unroll
  for (int t = 0; t < 8; ++t) {
    const int s = t * 64 + lane;            // 0..511
    const int row = (wave & 1) * 32 + (s >> 4);
    const int oct = s & 15;                 // 16B-octet within 128-feat row
    const float* sp = src_w + (size_t)row * HH + oct * 8;
    float4 f0 = *(const float4*)sp;
    float4 f1 = *(const float4*)(sp + 4);
    uint4 pk;
    pk.x = pack2(f0.x, f0.y);
    pk.y = pack2(f0.z, f0.w);
    pk.z = pack2(f1.x, f1.y);
    pk.w = pack2(f1.z, f1.w);
    const int kc = sel * 4 + (oct >> 2);
    const int o = oct & 3;
    const int ph = o ^ ((row & 3) ^ ((row >> 2) & 3)) ^ sel;  // kc>>2 == sel
    *(uint4*)&Abuf[(kc * 64 + row) * 32 + ph * 8] = pk;
  }
  __syncthreads();

  // ---- K-loop: barrier-free, B 1-deep prefetch, even/odd register sets ----
  const int l15 = lane & 15;
  const int quad = lane >> 4;
  const int sl = (l15 & 3) ^ ((l15 >> 2) & 3);
  const int physB = quad ^ sl;

  // q-slice base is wave-uniform -> SGPR; per-lane state is 4 u32 offsets.
  const char* __restrict__ Wq = (const char*)(Wc + (size_t)q * 262144);
  u32 offb[4];
#pragma unroll
  for (int gg = 0; gg < 4; ++gg) {
    const int n = gg * 128 + wave * 16 + l15;
    offb[gg] = (u32)((n * 4 + physB) * 16);
  }

  f32x4 acc[4][4];
#pragma unroll
  for (int rt = 0; rt < 4; ++rt)
#pragma unroll
    for (int gg = 0; gg < 4; ++gg) acc[rt][gg] = (f32x4)0.f;

  bf16x8 bA[4], bB[4];
#pragma unroll
  for (int gg = 0; gg < 4; ++gg) bA[gg] = *(const bf16x8*)(Wq + offb[gg]);

#pragma unroll
  for (int kp = 0; kp < 8; ++kp) {
    const int kc0 = 2 * kp;
    const int kc1 = 2 * kp + 1;
    // prefetch kc1 into bB (1-deep, lands during kc0's MFMAs)
    {
      const u32 kb = (u32)kc1 * 32768u;
#pragma unroll
      for (int gg = 0; gg < 4; ++gg)
        bB[gg] = *(const bf16x8*)(Wq + (kb + offb[gg]));
    }
    MFMA_BODY(kc0, bA);
    // prefetch kc0+2 into bA
    if (kp < 7) {
      const u32 kb = (u32)(kc1 + 1) * 32768u;
#pragma unroll
      for (int gg = 0; gg < 4; ++gg)
        bA[gg] = *(const bf16x8*)(Wq + (kb + offb[gg]));
    }
    MFMA_BODY(kc1, bB);
  }

  // ---- epilogue: tanh / sigmoid / softmax-of-3 / weighted state sum ----
  const float* bcq = bcat + q * 512;
  const float* beq = bexp + q * 384;
  const size_t outbase = (size_t)((q * 32 + b) * 512 + s_base) * HH;
  const int h = wave * 16 + l15;  // 0..127
  const float bc0 = bcq[h];
  const float bc1 = bcq[128 + h];
  const float bc2 = bcq[256 + h];
  const float bc3 = bcq[384 + h];
  const float be1 = beq[h];
  const float be2 = beq[128 + h];
  const float be3 = beq[256 + h];
  const int kcc = h >> 5;         // CNN chunk (0..3)
  const int kce = 12 + (h >> 5);  // exper chunk (12..15)
  const int oh = (h >> 3) & 3;
  const int he = h & 7;
#pragma unroll
  for (int rt = 0; rt < 4; ++rt) {
#pragma unroll
    for (int r = 0; r < 4; ++r) {
      const int row = rt * 16 + quad * 4 + r;
      const int srw = (row & 3) ^ ((row >> 2) & 3);
      const float cnn = bf2f(Abuf[(kcc * 64 + row) * 32 + (oh ^ srw) * 8 + he]);
      const float ex =
          bf2f(Abuf[(kce * 64 + row) * 32 + (oh ^ srw ^ 3) * 8 + he]);
      const float c0 = acc[rt][0][r] + bc0;
      const float p1 = acc[rt][1][r] + bc1 + be1;
      const float p2 = acc[rt][2][r] + bc2 + be2;
      const float p3 = acc[rt][3][r] + bc3 + be3;
      const float e2c = __expf(2.f * c0);
      const float ns = 1.f - 2.f * __builtin_amdgcn_rcpf(e2c + 1.f);  // tanh
      const float g1 = __builtin_amdgcn_rcpf(1.f + __expf(-p1));
      const float g2 = __builtin_amdgcn_rcpf(1.f + __expf(-p2));
      const float g3 = __builtin_amdgcn_rcpf(1.f + __expf(-p3));
      const float e1 = __expf(g1);
      const float e2 = __expf(g2);
      const float e3 = __expf(g3);
      const float inv = __builtin_amdgcn_rcpf(e1 + e2 + e3);
      out[outbase + (size_t)row * HH + h] = (e1 * ns + e2 * cnn + e3 * ex) * inv;
    }
  }
}

extern "C" void kernel_launch(void* const* d_in, const int* in_sizes, int n_in,
                              void* d_out, int out_size, void* d_ws, size_t ws_size,
                              hipStream_t stream) {
  const float* CNN = (const float*)d_in[0];
  const float* gaz = (const float*)d_in[1];
  const float* gazb = (const float*)d_in[2];
  const float* gm = (const float*)d_in[3];
  const float* exper = (const float*)d_in[4];
  const float* Wcat = (const float*)d_in[5];
  const float* bcat = (const float*)d_in[6];
  const float* Wexp = (const float*)d_in[7];
  const float* bexp = (const float*)d_in[8];
  u16* Wc = (u16*)d_ws;  // 2 MB fused bf16 weights

  prep_w<<<512, 256, 0, stream>>>(Wcat, Wexp, Wc);
  fused_gate<<<1024, 512, 0, stream>>>(CNN, gaz, gazb, gm, exper, Wc, bcat,
                                       bexp, (float*)d_out);
}

// Round 23
// 150.406 us; speedup vs baseline: 1.1795x; 1.0144x over previous
//
#include <hip/hip_runtime.h>

typedef unsigned short u16;
typedef unsigned int u32;
typedef short bf16x8 __attribute__((ext_vector_type(8)));
typedef float f32x4 __attribute__((ext_vector_type(4)));

#define HH 128

__device__ __forceinline__ u16 f2bf(float f) {
  u32 u = __float_as_uint(f);
  u += 0x7fffu + ((u >> 16) & 1u);  // round-to-nearest-even
  return (u16)(u >> 16);
}
__device__ __forceinline__ u32 pack2(float a, float b) {
  return (u32)f2bf(a) | ((u32)f2bf(b) << 16);
}

// ---------------------------------------------------------------------------
// Pre-pass: fused W_comb (bf16), chunk-transposed + bank-swizzled, into d_ws.
// Chunk index (((q*16+kc)*512+n)*4+p) holds W[k = kc*32 + lq*8 + j][col n],
// lq = p ^ (n&3) ^ ((n>>2)&3).
// Fused: k<384 -> W_cat[k][q*512+n]; k>=384 -> (n<128 ? 0 : W_exp[k-384][q*384+n-128])
// ---------------------------------------------------------------------------
__global__ __launch_bounds__(256) void prep_w(const float* __restrict__ Wcat,
                                              const float* __restrict__ Wexp,
                                              u16* __restrict__ Wc) {
  const int bx = blockIdx.x;      // 512 blocks: ((q*16+kc)*8 + nt)
  const int nt = bx & 7;
  const int kc = (bx >> 3) & 15;
  const int q = bx >> 7;
  __shared__ u16 T[32 * 72];      // [k-in-chunk][64 cols], stride 72 (pad)

  const int tid = threadIdx.x;
  const int r = tid >> 3;
  const int c8 = (tid & 7) * 8;
  float v[8];
  if (kc < 12) {
    const float* src =
        Wcat + (size_t)(kc * 32 + r) * 2048 + q * 512 + nt * 64 + c8;
    float4 a = *(const float4*)src;
    float4 b = *(const float4*)(src + 4);
    v[0] = a.x; v[1] = a.y; v[2] = a.z; v[3] = a.w;
    v[4] = b.x; v[5] = b.y; v[6] = b.z; v[7] = b.w;
  } else if (nt >= 2) {
    const float* src = Wexp + (size_t)((kc - 12) * 32 + r) * 1536 + q * 384 +
                       nt * 64 + c8 - 128;
    float4 a = *(const float4*)src;
    float4 b = *(const float4*)(src + 4);
    v[0] = a.x; v[1] = a.y; v[2] = a.z; v[3] = a.w;
    v[4] = b.x; v[5] = b.y; v[6] = b.z; v[7] = b.w;
  } else {
#pragma unroll
    for (int j = 0; j < 8; ++j) v[j] = 0.f;
  }
  uint4 pk;
  pk.x = pack2(v[0], v[1]);
  pk.y = pack2(v[2], v[3]);
  pk.z = pack2(v[4], v[5]);
  pk.w = pack2(v[6], v[7]);
  *(uint4*)&T[r * 72 + c8] = pk;
  __syncthreads();

  const int p = tid & 3;
  const int nl = tid >> 2;  // 0..63 local col
  const int lq = p ^ (nl & 3) ^ ((nl >> 2) & 3);
  u16 w[8];
#pragma unroll
  for (int j = 0; j < 8; ++j) w[j] = T[(lq * 8 + j) * 72 + nl];
  uint4 o;
  o.x = (u32)w[0] | ((u32)w[1] << 16);
  o.y = (u32)w[2] | ((u32)w[3] << 16);
  o.z = (u32)w[4] | ((u32)w[5] << 16);
  o.w = (u32)w[6] | ((u32)w[7] << 16);
  const size_t idx = ((size_t)((q * 16 + kc) * 512) + nt * 64 + nl) * 4 + p;
  ((uint4*)Wc)[idx] = o;
}

// ---------------------------------------------------------------------------
// R5 = R4 (measured 52.7-57.1 us) + epilogue cnn/ex from GLOBAL fp32.
// R1/R4's epilogue read cnn/ex from Abuf: row-stride 64B at fixed h => 4-way
// bank conflict (SQ_LDS_BANK_CONFLICT pinned at 3.1M). R2 validated the fix
// (cnn from global: conflicts down, absmax unchanged, tiles L2-hot from the
// stage pass). Removes all 32 epilogue LDS reads + bf2f unpacks per wave.
// Everything else verbatim R4: barrier-free K-loop, even/odd B reg rotation,
// 1-deep prefetch, 2 blocks/CU, 64 VGPR + 64 AGPR.
// ---------------------------------------------------------------------------
#define MFMA_BODY(KC, BREG)                                                    \
  {                                                                            \
    const int pa = (quad ^ sl ^ ((KC) >> 2)) * 8;                              \
    const u16* ab = &Abuf[((KC)*64 + l15) * 32 + pa];                          \
    bf16x8 af0 = *(const bf16x8*)(ab);                                         \
    bf16x8 af1 = *(const bf16x8*)(ab + 16 * 32);                               \
    __builtin_amdgcn_s_setprio(1);                                             \
    acc[0][0] = __builtin_amdgcn_mfma_f32_16x16x32_bf16(af0, BREG[0], acc[0][0], 0, 0, 0); \
    acc[0][1] = __builtin_amdgcn_mfma_f32_16x16x32_bf16(af0, BREG[1], acc[0][1], 0, 0, 0); \
    acc[0][2] = __builtin_amdgcn_mfma_f32_16x16x32_bf16(af0, BREG[2], acc[0][2], 0, 0, 0); \
    acc[0][3] = __builtin_amdgcn_mfma_f32_16x16x32_bf16(af0, BREG[3], acc[0][3], 0, 0, 0); \
    acc[1][0] = __builtin_amdgcn_mfma_f32_16x16x32_bf16(af1, BREG[0], acc[1][0], 0, 0, 0); \
    acc[1][1] = __builtin_amdgcn_mfma_f32_16x16x32_bf16(af1, BREG[1], acc[1][1], 0, 0, 0); \
    acc[1][2] = __builtin_amdgcn_mfma_f32_16x16x32_bf16(af1, BREG[2], acc[1][2], 0, 0, 0); \
    acc[1][3] = __builtin_amdgcn_mfma_f32_16x16x32_bf16(af1, BREG[3], acc[1][3], 0, 0, 0); \
    __builtin_amdgcn_s_setprio(0);                                             \
    bf16x8 af2 = *(const bf16x8*)(ab + 32 * 32);                               \
    bf16x8 af3 = *(const bf16x8*)(ab + 48 * 32);                               \
    __builtin_amdgcn_s_setprio(1);                                             \
    acc[2][0] = __builtin_amdgcn_mfma_f32_16x16x32_bf16(af2, BREG[0], acc[2][0], 0, 0, 0); \
    acc[2][1] = __builtin_amdgcn_mfma_f32_16x16x32_bf16(af2, BREG[1], acc[2][1], 0, 0, 0); \
    acc[2][2] = __builtin_amdgcn_mfma_f32_16x16x32_bf16(af2, BREG[2], acc[2][2], 0, 0, 0); \
    acc[2][3] = __builtin_amdgcn_mfma_f32_16x16x32_bf16(af2, BREG[3], acc[2][3], 0, 0, 0); \
    acc[3][0] = __builtin_amdgcn_mfma_f32_16x16x32_bf16(af3, BREG[0], acc[3][0], 0, 0, 0); \
    acc[3][1] = __builtin_amdgcn_mfma_f32_16x16x32_bf16(af3, BREG[1], acc[3][1], 0, 0, 0); \
    acc[3][2] = __builtin_amdgcn_mfma_f32_16x16x32_bf16(af3, BREG[2], acc[3][2], 0, 0, 0); \
    acc[3][3] = __builtin_amdgcn_mfma_f32_16x16x32_bf16(af3, BREG[3], acc[3][3], 0, 0, 0); \
    __builtin_amdgcn_s_setprio(0);                                             \
  }

__global__ __launch_bounds__(512, 4) void fused_gate(
    const float* __restrict__ CNN, const float* __restrict__ gaz,
    const float* __restrict__ gazb, const float* __restrict__ gm,
    const float* __restrict__ exper, const u16* __restrict__ Wc,
    const float* __restrict__ bcat, const float* __restrict__ bexp,
    float* __restrict__ out) {
  __shared__ u16 Abuf[16 * 64 * 32];  // 64 KB

  const int tid = threadIdx.x;
  const int lane = tid & 63;
  const int wave = tid >> 6;  // 0..7
  const int bx = blockIdx.x;  // 1024: grp*8 + tile
  const int tile = bx & 7;
  const int grp = bx >> 3;
  const int b = grp >> 2;
  const int q = grp & 3;
  const int s_base = tile * 64;

  // ---- stage A: wave pair (sel = wave>>1) loads source sel; wave&1 picks
  //      the 32-row half. Each wave: 32 rows x 128 feats (16 KB fp32).
  const int sel = wave >> 1;
  const float* src_w =
      (sel == 0) ? CNN + (size_t)(b * 2048 + q * 512 + s_base) * HH
      : (sel == 1) ? (((q & 1) ? gazb : gaz) + (size_t)(b * 512 + s_base) * HH)
      : (sel == 2) ? gm + (size_t)(b * 512 + s_base) * HH
                   : exper + (size_t)(b * 512 + s_base) * HH;
#pragma unroll
  for (int t = 0; t < 8; ++t) {
    const int s = t * 64 + lane;            // 0..511
    const int row = (wave & 1) * 32 + (s >> 4);
    const int oct = s & 15;                 // 16B-octet within 128-feat row
    const float* sp = src_w + (size_t)row * HH + oct * 8;
    float4 f0 = *(const float4*)sp;
    float4 f1 = *(const float4*)(sp + 4);
    uint4 pk;
    pk.x = pack2(f0.x, f0.y);
    pk.y = pack2(f0.z, f0.w);
    pk.z = pack2(f1.x, f1.y);
    pk.w = pack2(f1.z, f1.w);
    const int kc = sel * 4 + (oct >> 2);
    const int o = oct & 3;
    const int ph = o ^ ((row & 3) ^ ((row >> 2) & 3)) ^ sel;  // kc>>2 == sel
    *(uint4*)&Abuf[(kc * 64 + row) * 32 + ph * 8] = pk;
  }
  __syncthreads();

  // ---- K-loop: barrier-free, B 1-deep prefetch, even/odd register sets ----
  const int l15 = lane & 15;
  const int quad = lane >> 4;
  const int sl = (l15 & 3) ^ ((l15 >> 2) & 3);
  const int physB = quad ^ sl;

  // q-slice base is wave-uniform -> SGPR; per-lane state is 4 u32 offsets.
  const char* __restrict__ Wq = (const char*)(Wc + (size_t)q * 262144);
  u32 offb[4];
#pragma unroll
  for (int gg = 0; gg < 4; ++gg) {
    const int n = gg * 128 + wave * 16 + l15;
    offb[gg] = (u32)((n * 4 + physB) * 16);
  }

  f32x4 acc[4][4];
#pragma unroll
  for (int rt = 0; rt < 4; ++rt)
#pragma unroll
    for (int gg = 0; gg < 4; ++gg) acc[rt][gg] = (f32x4)0.f;

  bf16x8 bA[4], bB[4];
#pragma unroll
  for (int gg = 0; gg < 4; ++gg) bA[gg] = *(const bf16x8*)(Wq + offb[gg]);

#pragma unroll
  for (int kp = 0; kp < 8; ++kp) {
    const int kc0 = 2 * kp;
    const int kc1 = 2 * kp + 1;
    // prefetch kc1 into bB (1-deep, lands during kc0's MFMAs)
    {
      const u32 kb = (u32)kc1 * 32768u;
#pragma unroll
      for (int gg = 0; gg < 4; ++gg)
        bB[gg] = *(const bf16x8*)(Wq + (kb + offb[gg]));
    }
    MFMA_BODY(kc0, bA);
    // prefetch kc0+2 into bA
    if (kp < 7) {
      const u32 kb = (u32)(kc1 + 1) * 32768u;
#pragma unroll
      for (int gg = 0; gg < 4; ++gg)
        bA[gg] = *(const bf16x8*)(Wq + (kb + offb[gg]));
    }
    MFMA_BODY(kc1, bB);
  }

  // ---- epilogue: tanh / sigmoid / softmax-of-3 / weighted state sum ----
  // cnn/ex from GLOBAL fp32 (L2-hot from stage) — no LDS reads, no conflicts.
  const float* bcq = bcat + q * 512;
  const float* beq = bexp + q * 384;
  const size_t outbase = (size_t)((q * 32 + b) * 512 + s_base) * HH;
  const int h = wave * 16 + l15;  // 0..127
  const float bc0 = bcq[h];
  const float bc1 = bcq[128 + h];
  const float bc2 = bcq[256 + h];
  const float bc3 = bcq[384 + h];
  const float be1 = beq[h];
  const float be2 = beq[128 + h];
  const float be3 = beq[256 + h];
  const float* cnnb = CNN + (size_t)(b * 2048 + q * 512 + s_base) * HH + h;
  const float* expb = exper + (size_t)(b * 512 + s_base) * HH + h;
#pragma unroll
  for (int rt = 0; rt < 4; ++rt) {
#pragma unroll
    for (int r = 0; r < 4; ++r) {
      const int row = rt * 16 + quad * 4 + r;
      const float cnn = cnnb[(size_t)row * HH];
      const float ex = expb[(size_t)row * HH];
      const float c0 = acc[rt][0][r] + bc0;
      const float p1 = acc[rt][1][r] + bc1 + be1;
      const float p2 = acc[rt][2][r] + bc2 + be2;
      const float p3 = acc[rt][3][r] + bc3 + be3;
      const float e2c = __expf(2.f * c0);
      const float ns = 1.f - 2.f * __builtin_amdgcn_rcpf(e2c + 1.f);  // tanh
      const float g1 = __builtin_amdgcn_rcpf(1.f + __expf(-p1));
      const float g2 = __builtin_amdgcn_rcpf(1.f + __expf(-p2));
      const float g3 = __builtin_amdgcn_rcpf(1.f + __expf(-p3));
      const float e1 = __expf(g1);
      const float e2 = __expf(g2);
      const float e3 = __expf(g3);
      const float inv = __builtin_amdgcn_rcpf(e1 + e2 + e3);
      out[outbase + (size_t)row * HH + h] = (e1 * ns + e2 * cnn + e3 * ex) * inv;
    }
  }
}

extern "C" void kernel_launch(void* const* d_in, const int* in_sizes, int n_in,
                              void* d_out, int out_size, void* d_ws, size_t ws_size,
                              hipStream_t stream) {
  const float* CNN = (const float*)d_in[0];
  const float* gaz = (const float*)d_in[1];
  const float* gazb = (const float*)d_in[2];
  const float* gm = (const float*)d_in[3];
  const float* exper = (const float*)d_in[4];
  const float* Wcat = (const float*)d_in[5];
  const float* bcat = (const float*)d_in[6];
  const float* Wexp = (const float*)d_in[7];
  const float* bexp = (const float*)d_in[8];
  u16* Wc = (u16*)d_ws;  // 2 MB fused bf16 weights

  prep_w<<<512, 256, 0, stream>>>(Wcat, Wexp, Wc);
  fused_gate<<<1024, 512, 0, stream>>>(CNN, gaz, gazb, gm, exper, Wc, bcat,
                                       bexp, (float*)d_out);
}